// Round 6
// baseline (447.585 us; speedup 1.0000x reference)
//
#include <hip/hip_runtime.h>

// Problem constants (fixed by setup_inputs).
#define N_SAMP 80
#define C_CH   2048
#define HW     256          // 16*16
#define S_TOP  512
#define HW4    64           // HW / 4 (float4 per channel)

// ---------------------------------------------------------------------------
// Kernel 1: per-row O(C) rank via bucket histogram (replaces the per-wave
// ballot scan that was ~43 us of redundant VALU on the streaming path).
//
// Scores are uniform[0,1) -> bucket = clamp(floor(s*2048), 0, 2047) is
// ~uniformly occupied (Poisson(1)) and MONOTONE in s: bucket_j > bucket_i
// implies s_j > s_i (floor(fl(s*2048)) is monotone non-decreasing; clamping
// only merges the extreme buckets). Hence:
//   rank(i) = cumgt[b_i] + #{ j in bucket b_i : key_j > key_i }
// with the exact-tie-break packed key (verified rounds 0-5):
//   key(i) = (monotone(float bits) << 11) | (2047 - i)
// (value desc, index asc on ties == jax.lax.top_k).
//
// One block (256 thr) per row; ~45 KB LDS; avg ~1 within-bucket compare per
// channel. Emits pcmap[n][ch] = rank<512 ? rand_index[n][rank] : -1, so the
// main kernel needs NO rank logic at all.
// ---------------------------------------------------------------------------
__global__ __launch_bounds__(256) void rank_hist_kernel(
    const float* __restrict__ s_ca, const int* __restrict__ rand_index,
    int* __restrict__ pcmap) {
  __shared__ unsigned int keys[C_CH];        // 8 KB  monotone u32 score bits
  __shared__ unsigned short bkt[C_CH];       // 4 KB  bucket per channel
  __shared__ int hist[C_CH];                 // 8 KB  counts -> place offsets
  __shared__ int cumgt[C_CH];                // 8 KB  #elements in buckets > b
  __shared__ unsigned long long sorted[C_CH];// 16 KB bucket-grouped keys
  __shared__ int chunk[256];                 // 1 KB  per-thread chunk sums

  const int n = blockIdx.x;
  const int t = threadIdx.x;
  const float* __restrict__ row = s_ca + (size_t)n * C_CH;

  for (int i = t; i < C_CH; i += 256) hist[i] = 0;
  __syncthreads();

  for (int i = t; i < C_CH; i += 256) {
    const float s = row[i];
    unsigned int mb = __float_as_uint(s);
    mb ^= (mb & 0x80000000u) ? 0xFFFFFFFFu : 0x80000000u;
    keys[i] = mb;
    int b = (int)(s * 2048.0f);
    b = (b < 0) ? 0 : ((b > 2047) ? 2047 : b);
    bkt[i] = (unsigned short)b;
    atomicAdd(&hist[b], 1);
  }
  __syncthreads();

  // Per-thread chunk sums (8 buckets each) -> inclusive prefix scan.
  {
    int cs = 0;
#pragma unroll
    for (int k = 0; k < 8; ++k) cs += hist[t * 8 + k];
    chunk[t] = cs;
  }
  __syncthreads();
  for (int d = 1; d < 256; d <<= 1) {
    const int add = (t >= d) ? chunk[t - d] : 0;
    __syncthreads();
    chunk[t] += add;
    __syncthreads();
  }
  const int total = chunk[255];  // == 2048

  // Suffix counts: cumgt[b] = #elements in buckets > b.
  {
    int run = total - chunk[t];  // elements in chunks above t
#pragma unroll
    for (int k = 7; k >= 0; --k) {
      cumgt[t * 8 + k] = run;
      run += hist[t * 8 + k];
    }
  }
  __syncthreads();

  // Reuse hist as placement offsets.
  for (int i = t; i < C_CH; i += 256) hist[i] = 0;
  __syncthreads();

  // Counting-sort placement: bucket b occupies [cumgt[b], cumgt[b]+count).
  for (int i = t; i < C_CH; i += 256) {
    const int b = bkt[i];
    const unsigned long long key =
        ((unsigned long long)keys[i] << 11) |
        (unsigned long long)(C_CH - 1 - i);
    const int pos = cumgt[b] + atomicAdd(&hist[b], 1);
    sorted[pos] = key;
  }
  __syncthreads();

  // Exact rank = cumgt[b] + within-bucket count; emit partner-channel map.
  int* __restrict__ pm = pcmap + (size_t)n * C_CH;
  const int* __restrict__ ri = rand_index + (size_t)n * S_TOP;
  for (int i = t; i < C_CH; i += 256) {
    const int b = bkt[i];
    const int lo = cumgt[b];
    const int nb = ((b > 0) ? cumgt[b - 1] : total) - lo;
    const unsigned long long mykey =
        ((unsigned long long)keys[i] << 11) |
        (unsigned long long)(C_CH - 1 - i);
    int r = lo;
    for (int p = lo; p < lo + nb; ++p) r += (sorted[p] > mykey) ? 1 : 0;
    pm[i] = (r < S_TOP) ? ri[r] : -1;
  }
}

// ---------------------------------------------------------------------------
// Kernel 2: pure streaming output (R5 wave structure, scan deleted).
// Block = 4 waves; wave owns 4 consecutive channels of row n; produces both
// output rows per channel:
//   plain: x[n,c,:] * s
//   aug  : pc>=0 ? (0.7*x[n,c,:] + 0.3*x[jn,pc,:]) * s : plain
// pc comes from pcmap (wave-uniform); aug branch wave-uniform; x read once.
// ---------------------------------------------------------------------------
__global__ __launch_bounds__(256) void stream_out_kernel(
    const float4* __restrict__ x4, const float* __restrict__ s_ca,
    const int* __restrict__ pcmap, const int* __restrict__ partner,
    float4* __restrict__ out4) {
  const unsigned int lane = threadIdx.x & 63u;
  const unsigned int wid = threadIdx.x >> 6;       // 0..3
  const unsigned int blk = blockIdx.x;             // 0..10239
  const unsigned int n = blk >> 7;                 // row
  const unsigned int ch0 = ((blk & 127u) << 4) | (wid << 2);
  const unsigned int g = n >> 4;   // way group
  const unsigned int b = n & 15u;  // index within group

  // Scores for this wave's 4 channels (one float4).
  const float4 sq = ((const float4*)(s_ca + (size_t)n * C_CH))[ch0 >> 2];
  const float si[4] = {sq.x, sq.y, sq.z, sq.w};

  // Partner row (scalar).
  int jn = (int)n + 1 + partner[n];
  if (jn >= N_SAMP) jn -= N_SAMP;

  // Partner-channel map for the 4 channels (wave-uniform values).
  int pc[4];
#pragma unroll
  for (int c = 0; c < 4; ++c) pc[c] = pcmap[(size_t)n * C_CH + ch0 + c];

  // Main x rows.
  float4 v[4];
#pragma unroll
  for (int c = 0; c < 4; ++c)
    v[c] = x4[(((size_t)n * C_CH + ch0 + c) << 6) | lane];

  // Output bases (float4 units): plain m = g*32+b, aug m = g*32+16+b.
  const size_t base_plain =
      (((size_t)((g << 5) | b) * C_CH + ch0) << 6) | lane;
  const size_t aug_off = ((size_t)(16 * C_CH)) << 6;

#pragma unroll
  for (int c = 0; c < 4; ++c) {
    const float s = si[c];
    float4 pv = make_float4(v[c].x * s, v[c].y * s, v[c].z * s, v[c].w * s);
    float4 av = pv;
    if (pc[c] >= 0) {  // wave-uniform branch
      const float4 u =
          x4[((((size_t)jn << 11) | (size_t)pc[c]) << 6) | lane];
      av.x = (0.7f * v[c].x + 0.3f * u.x) * s;
      av.y = (0.7f * v[c].y + 0.3f * u.y) * s;
      av.z = (0.7f * v[c].z + 0.3f * u.z) * s;
      av.w = (0.7f * v[c].w + 0.3f * u.w) * s;
    }
    out4[base_plain + ((size_t)c << 6)] = pv;
    out4[base_plain + aug_off + ((size_t)c << 6)] = av;
  }
}

extern "C" void kernel_launch(void* const* d_in, const int* in_sizes, int n_in,
                              void* d_out, int out_size, void* d_ws,
                              size_t ws_size, hipStream_t stream) {
  const float* x = (const float*)d_in[0];
  const float* s_ca = (const float*)d_in[1];
  const int* rand_index = (const int*)d_in[2];
  const int* partner = (const int*)d_in[3];
  // d_in[4] = shuffle_num (512, fixed by setup)

  int* pcmap = (int*)d_ws;  // N_SAMP * C_CH ints = 655,360 B

  rank_hist_kernel<<<N_SAMP, 256, 0, stream>>>(s_ca, rand_index, pcmap);

  // 4 waves/block x 4 channels/wave = 16 channels/block:
  // 80 * 2048 / 16 = 10,240 blocks.
  const int nblocks = (N_SAMP * C_CH) / 16;
  stream_out_kernel<<<nblocks, 256, 0, stream>>>(
      (const float4*)x, s_ca, pcmap, partner, (float4*)d_out);
}